// Round 1
// baseline (189.723 us; speedup 1.0000x reference)
//
#include <hip/hip_runtime.h>

// Problem: B=8, T=4096, H=1024, all fp32.
// score[b,t] = states[b,t,:] . (W[0] @ ctx[b,:]) + bias
//
// Timed region = harness poison fills (2 x ~77us, untouchable) + K1 + K2.
// K1: v[b,i] = W[i,:] . ctx[b,:]  -- W is 4 MiB, read ONCE (one wave per row,
//     all 8 b's per wave; ctx 32 KiB stays L1-hot).
// K2: out[b,t] = states[b,t,:] . v[b,:] + bias -- pure 128 MiB stream,
//     v held in 16 VGPRs per wave, 4 rows/wave => 16 NT loads in flight.

#define HDIM 1024
#define BDIM 8
#define TDIM 4096
#define RPW  4      // rows per wave in K2; must divide TDIM

// native clang vector type — required by __builtin_nontemporal_load
typedef float v4f __attribute__((ext_vector_type(4)));

// ---------- Kernel 1: one wave per W row i, computes v[b,i] for all b ----------
__global__ __launch_bounds__(256) void gs_compute_v(
    const float* __restrict__ W,
    const float* __restrict__ ctx,
    float* __restrict__ v)
{
    const int wave = (blockIdx.x << 2) | (threadIdx.x >> 6);   // i in [0,1024)
    const int lane = threadIdx.x & 63;

    const v4f* __restrict__ Wrow = (const v4f*)(W + (size_t)wave * HDIM);
    const v4f* __restrict__ C    = (const v4f*)ctx;            // (B, H) as v4f

    float acc[BDIM];
#pragma unroll
    for (int b = 0; b < BDIM; ++b) acc[b] = 0.0f;

#pragma unroll
    for (int k = 0; k < 4; ++k) {        // 4 * 64 lanes * 4 floats = 1024 = H
        v4f w4 = Wrow[k * 64 + lane];
#pragma unroll
        for (int b = 0; b < BDIM; ++b) {
            v4f c4 = C[b * (HDIM / 4) + k * 64 + lane];
            acc[b] += w4.x * c4.x + w4.y * c4.y + w4.z * c4.z + w4.w * c4.w;
        }
    }

#pragma unroll
    for (int b = 0; b < BDIM; ++b) {
#pragma unroll
        for (int off = 32; off > 0; off >>= 1)
            acc[b] += __shfl_down(acc[b], off, 64);
    }

    if (lane == 0) {
#pragma unroll
        for (int b = 0; b < BDIM; ++b)
            v[b * HDIM + wave] = acc[b];
    }
}

// ---------- Kernel 2: 4 contiguous rows per wave, v register-resident ----------
__global__ __launch_bounds__(256) void gs_compute_scores(
    const float* __restrict__ states,
    const float* __restrict__ v,
    const float* __restrict__ bias,
    float* __restrict__ out)
{
    const int wave = (blockIdx.x << 2) | (threadIdx.x >> 6);   // [0, 8192)
    const int lane = threadIdx.x & 63;
    const int row0 = wave * RPW;                               // [0, B*T)
    const int b = row0 >> 12;        // T=4096; RPW | T => whole wave same b

    // v[b,:] -> 16 VGPRs, reused for all RPW rows
    const v4f* __restrict__ V = (const v4f*)(v + (size_t)b * HDIM);
    const v4f vr0 = V[0 * 64 + lane];
    const v4f vr1 = V[1 * 64 + lane];
    const v4f vr2 = V[2 * 64 + lane];
    const v4f vr3 = V[3 * 64 + lane];
    const float bb = bias[0];

#pragma unroll
    for (int r = 0; r < RPW; ++r) {
        const v4f* __restrict__ S = (const v4f*)(states + (size_t)(row0 + r) * HDIM);
        v4f s0 = __builtin_nontemporal_load(&S[0 * 64 + lane]);
        v4f s1 = __builtin_nontemporal_load(&S[1 * 64 + lane]);
        v4f s2 = __builtin_nontemporal_load(&S[2 * 64 + lane]);
        v4f s3 = __builtin_nontemporal_load(&S[3 * 64 + lane]);

        float acc = s0.x * vr0.x + s0.y * vr0.y + s0.z * vr0.z + s0.w * vr0.w;
        acc      += s1.x * vr1.x + s1.y * vr1.y + s1.z * vr1.z + s1.w * vr1.w;
        acc      += s2.x * vr2.x + s2.y * vr2.y + s2.z * vr2.z + s2.w * vr2.w;
        acc      += s3.x * vr3.x + s3.y * vr3.y + s3.z * vr3.z + s3.w * vr3.w;

#pragma unroll
        for (int off = 32; off > 0; off >>= 1)
            acc += __shfl_down(acc, off, 64);

        if (lane == 0) out[row0 + r] = acc + bb;
    }
}

extern "C" void kernel_launch(void* const* d_in, const int* in_sizes, int n_in,
                              void* d_out, int out_size, void* d_ws, size_t ws_size,
                              hipStream_t stream)
{
    const float* states = (const float*)d_in[0];  // (B, T, H)
    const float* ctx    = (const float*)d_in[1];  // (B, H)
    const float* W      = (const float*)d_in[2];  // (1, H, H)
    const float* bias   = (const float*)d_in[3];  // (1,)
    float* out = (float*)d_out;                   // (B, T, 1) fp32
    float* v   = (float*)d_ws;                    // B*H floats = 32 KiB scratch

    gs_compute_v<<<dim3(HDIM / 4), dim3(256), 0, stream>>>(W, ctx, v);
    gs_compute_scores<<<dim3((BDIM * TDIM) / (4 * RPW)), dim3(256), 0, stream>>>(states, v, bias, out);
}